// Round 13
// baseline (176.002 us; speedup 1.0000x reference)
//
#include <hip/hip_runtime.h>
#include <hip/hip_bf16.h>

#define S_LEN 2048
#define D_DIM 1024

typedef float f32x4 __attribute__((ext_vector_type(4)));
typedef float f32x16 __attribute__((ext_vector_type(16)));
typedef short short8 __attribute__((ext_vector_type(8)));
typedef unsigned short us4 __attribute__((ext_vector_type(4)));
typedef unsigned int u32x4 __attribute__((ext_vector_type(4)));

using bf16 = __hip_bfloat16;

#define GLOBAL_AS(p) ((const __attribute__((address_space(1))) void*)(p))
#define LDS_AS(p) ((__attribute__((address_space(3))) void*)(p))

static __device__ __forceinline__ unsigned short f2bf(float f) {
  bf16 h = __float2bfloat16(f);
  return *reinterpret_cast<unsigned short*>(&h);
}
static __device__ __forceinline__ float bf2f(unsigned short u) {
  unsigned int w = ((unsigned int)u) << 16;
  return __builtin_bit_cast(float, w);
}

// ---------------- mask dtype probe: 0=int32, 1=uint8, 2=float32 ----------------
__global__ void detect_mask_kernel(const unsigned int* __restrict__ m, int* __restrict__ flag) {
  __shared__ int sh;
  if (threadIdx.x == 0) sh = 0;
  __syncthreads();
  int f = 0;
  for (int i = threadIdx.x; i < 4096; i += 256) {
    unsigned int w = m[i];
    if (w == 0x3f800000u) f |= 2;
    if (w & 0xFFFFFF00u) f |= 1;
  }
  if (f) atomicOr(&sh, f);
  __syncthreads();
  if (threadIdx.x == 0) *flag = (sh & 2) ? 2 : ((sh & 1) ? 1 : 0);
}

// ---------------- fused positional-encoding + LayerNorm -> bf16 ----------------
__global__ __launch_bounds__(256) void pe_ln_kernel(
    const float* __restrict__ x, const float* __restrict__ lnw,
    const float* __restrict__ lnb, bf16* __restrict__ out) {
  const int row = blockIdx.x;
  const int s = row & (S_LEN - 1);
  const int tid = threadIdx.x;
  const float pos = (float)s;
  const float* base = x + (size_t)row * D_DIM;

  f32x4 v = *(const f32x4*)(base + tid * 4);
  float h[4];
#pragma unroll
  for (int r = 0; r < 4; ++r) {
    int d = tid * 4 + r;
    float dv = (float)d * (2.0f / 1024.0f);
    float freq = exp2f(dv * -13.287712379549449f);
    float pe = pos * freq;
    float pv = (d & 1) ? __cosf(pe) : __sinf(pe);
    h[r] = pv + v[r];
  }
  float ss = h[0] + h[1] + h[2] + h[3];
#pragma unroll
  for (int o = 32; o >= 1; o >>= 1) ss += __shfl_xor(ss, o);
  __shared__ float red[8];
  const int wave = tid >> 6, lane = tid & 63;
  if (lane == 0) red[wave] = ss;
  __syncthreads();
  const float mu = (red[0] + red[1] + red[2] + red[3]) * (1.0f / 1024.0f);
  float sq = 0.f;
#pragma unroll
  for (int r = 0; r < 4; ++r) { float d0 = h[r] - mu; sq += d0 * d0; }
#pragma unroll
  for (int o = 32; o >= 1; o >>= 1) sq += __shfl_xor(sq, o);
  if (lane == 0) red[4 + wave] = sq;
  __syncthreads();
  const float var = (red[4] + red[5] + red[6] + red[7]) * (1.0f / 1024.0f);
  const float inv = rsqrtf(var + 1e-5f);
  f32x4 wv = *(const f32x4*)(lnw + tid * 4);
  f32x4 bv = *(const f32x4*)(lnb + tid * 4);
  us4 o4;
#pragma unroll
  for (int r = 0; r < 4; ++r) o4[r] = f2bf((h[r] - mu) * inv * wv[r] + bv[r]);
  *(us4*)((unsigned short*)out + (size_t)row * D_DIM + tid * 4) = o4;
}

// ---------------- Wk fp32 [K][N] -> bf16 transposed [N][K] ----------------
__global__ __launch_bounds__(256) void wk_to_bf16t_kernel(const float* __restrict__ wk,
                                                          bf16* __restrict__ wt) {
  __shared__ float t[32][33];
  const int n0 = blockIdx.x * 32, k0 = blockIdx.y * 32;
  const int tx = threadIdx.x & 31, ty = threadIdx.x >> 5;
#pragma unroll
  for (int i = 0; i < 32; i += 8)
    t[ty + i][tx] = wk[(size_t)(k0 + ty + i) * 1024 + n0 + tx];
  __syncthreads();
#pragma unroll
  for (int i = 0; i < 32; i += 8)
    wt[(size_t)(n0 + ty + i) * 1024 + k0 + tx] = __float2bfloat16(t[tx][ty + i]);
}

// ---------------- bf16 GEMM, C = A[M][K] * B_t[N][K]^T  (32x32 MFMA, multi-block/CU) ----
// 128x128 tile, BK=32, 256 thr / 4 waves (2M x 2N); per-wave 64x64 = 2x2 frags of
// 32x32x16 MFMA (128 B LDS-read per MFMA). LDS 32 KB total (2-deep) -> 4-5
// blocks/CU resident: one block's barrier drain overlaps other blocks' MFMA
// (m114 cross-block overlap — the piece 1-block/CU structures lacked).
// Stage-at-top + single __syncthreads per K-tile. XOR swizzle: store 16B slot
// (L&3)^((L>>3)&3); read slot orig^((row>>1)&3)  -> 2-way banks (free).
// EPI 0: + bias, write bf16 C row-major AND bf16 transposed copy
// EPI 1: * 1/32, write bf16 (mask applied later in softmax)
// EPI 2: plain fp32 write
template <int EPI>
__global__ __launch_bounds__(256) void gemm7_kernel(
    const bf16* __restrict__ A, int lda, long long A_bs,
    const bf16* __restrict__ B, int ldb, long long B_bs,
    int K,
    void* __restrict__ C, int ldc, long long C_bs,
    const float* __restrict__ bias, bf16* __restrict__ qkv_t) {
  __shared__ bf16 sbuf[2][256 * 32];  // A rows [0,128) at 0, B rows [0,128) at 4096

  const int tid = threadIdx.x;
  const int wid = tid >> 6, lane = tid & 63;
  const int wm = wid >> 1, wn = wid & 1;  // 2M x 2N wave grid

  // bijective XCD-aware swizzle (all grids % 8 == 0)
  const int gx = gridDim.x, gy = gridDim.y;
  const int nwg = gx * gy * gridDim.z;
  int lin = (blockIdx.z * gy + blockIdx.y) * gx + blockIdx.x;
  lin = (lin & 7) * (nwg >> 3) + (lin >> 3);
  const int bx = lin % gx;
  const int by = (lin / gx) % gy;
  const int z = lin / (gx * gy);

  const int m0 = by * 128;
  const int n0 = bx * 128;

  const bf16* Ab = A + (size_t)z * A_bs;
  const bf16* Bb = B + (size_t)z * B_bs;

  // staging: one gload_lds covers 16 rows x 32 k (1 KB); lane L -> row +(L>>2),
  // fetches global 16B slot (L&3)^((L>>3)&3) into linear LDS slot (L&3).
  const int grow = lane >> 2;
  const int gslot = ((lane & 3) ^ ((lane >> 3) & 3)) * 8;

  // wave w stages A rows [w*32,+32) and B rows [w*32,+32), 2 insts each
  const bf16* pa = Ab + (size_t)(m0 + wid * 32 + grow) * lda + gslot;
  const bf16* pb = Bb + (size_t)(n0 + wid * 32 + grow) * ldb + gslot;
  const int a_lds = (wid * 32) * 32;
  const int b_lds = 4096 + (wid * 32) * 32;

#define STAGE(bufi, kk)                                                          \
  do {                                                                           \
    bf16* D_ = &sbuf[bufi][0];                                                   \
    __builtin_amdgcn_global_load_lds(GLOBAL_AS(pa + (kk)),                       \
                                     LDS_AS(D_ + a_lds), 16, 0, 0);              \
    __builtin_amdgcn_global_load_lds(GLOBAL_AS(pa + (size_t)16 * lda + (kk)),    \
                                     LDS_AS(D_ + a_lds + 512), 16, 0, 0);        \
    __builtin_amdgcn_global_load_lds(GLOBAL_AS(pb + (kk)),                       \
                                     LDS_AS(D_ + b_lds), 16, 0, 0);              \
    __builtin_amdgcn_global_load_lds(GLOBAL_AS(pb + (size_t)16 * ldb + (kk)),    \
                                     LDS_AS(D_ + b_lds + 512), 16, 0, 0);        \
  } while (0)

  f32x16 acc[2][2];
#pragma unroll
  for (int i = 0; i < 2; ++i)
#pragma unroll
    for (int j = 0; j < 2; ++j) acc[i][j] = (f32x16)(0.0f);

  // fragment reads (32x32x16): row = base + (lane&31); k-slot orig = h*2+(lane>>5);
  // linear slot = orig ^ ((row>>1)&3)
  const int lrow = lane & 31;
  const int rsw = (lane >> 1) & 3;
  const int rdA = (wm * 64 + lrow) * 32;          // + i*1024 + koff
  const int rdB = 4096 + (wn * 64 + lrow) * 32;   // + j*1024 + koff

  const int NT = K >> 5;
  STAGE(0, 0);
  __syncthreads();  // buf0 resident
  int buf = 0;
  for (int kt = 0; kt < NT; ++kt) {
    if (kt + 1 < NT) STAGE(buf ^ 1, (size_t)(kt + 1) * 32);  // issue first
    const bf16* S = &sbuf[buf][0];
#pragma unroll
    for (int h = 0; h < 2; ++h) {
      const int koff = (((h * 2) + (lane >> 5)) ^ rsw) * 8;
      short8 a0 = *(const short8*)(S + rdA + koff);
      short8 a1 = *(const short8*)(S + rdA + 1024 + koff);
      short8 b0 = *(const short8*)(S + rdB + koff);
      short8 b1 = *(const short8*)(S + rdB + 1024 + koff);
      acc[0][0] = __builtin_amdgcn_mfma_f32_32x32x16_bf16(a0, b0, acc[0][0], 0, 0, 0);
      acc[0][1] = __builtin_amdgcn_mfma_f32_32x32x16_bf16(a0, b1, acc[0][1], 0, 0, 0);
      acc[1][0] = __builtin_amdgcn_mfma_f32_32x32x16_bf16(a1, b0, acc[1][0], 0, 0, 0);
      acc[1][1] = __builtin_amdgcn_mfma_f32_32x32x16_bf16(a1, b1, acc[1][1], 0, 0, 0);
    }
    __syncthreads();  // drains vmcnt (next tile resident) + all reads of buf done
    buf ^= 1;
  }
#undef STAGE

  // epilogue: 32x32 C/D layout col = lane&31, row = (reg&3)+8*(reg>>2)+4*(lane>>5)
  // [measured m74/m101]
  const int crow0 = 4 * (lane >> 5);
  const int ccol = lane & 31;
#pragma unroll
  for (int i = 0; i < 2; ++i) {
#pragma unroll
    for (int j = 0; j < 2; ++j) {
      const int col = n0 + wn * 64 + j * 32 + ccol;
#pragma unroll
      for (int q = 0; q < 4; ++q) {
        const int rr = m0 + wm * 64 + i * 32 + 8 * q + crow0;  // rows rr..rr+3
        if (EPI == 0) {
          const float bv = bias[col];
          us4 pack;
#pragma unroll
          for (int r = 0; r < 4; ++r) {
            unsigned short hb = f2bf(acc[i][j][4 * q + r] + bv);
            ((unsigned short*)C)[(size_t)(rr + r) * ldc + col] = hb;
            pack[r] = hb;
          }
          const int bb = rr >> 11, s = rr & 2047;
          *(us4*)((unsigned short*)qkv_t + (size_t)bb * (1024ll * 2048) +
                  (size_t)col * 2048 + s) = pack;
        } else if (EPI == 1) {
          unsigned short* Cb = (unsigned short*)C + (size_t)z * C_bs;
#pragma unroll
          for (int r = 0; r < 4; ++r)
            Cb[(size_t)(rr + r) * ldc + col] = f2bf(acc[i][j][4 * q + r] * 0.03125f);
        } else {
          float* Cb = (float*)C + (size_t)z * C_bs;
#pragma unroll
          for (int r = 0; r < 4; ++r)
            Cb[(size_t)(rr + r) * ldc + col] = acc[i][j][4 * q + r];
        }
      }
    }
  }
}

// ---------------- fused mask + in-place row softmax on bf16 scores ----------------
__global__ __launch_bounds__(256) void softmax_kernel(
    unsigned short* __restrict__ scores, const void* __restrict__ mask,
    const int* __restrict__ flagp) {
  const int row = blockIdx.x;  // 8192 rows = b*2048 + q
  const int fmode = *flagp;
  unsigned short* base = scores + (size_t)row * 2048;
  const int tid = threadIdx.x;
  const int wave = tid >> 6, lane = tid & 63;

  short8 v = *(const short8*)(base + tid * 8);
  float x[8];
#pragma unroll
  for (int r = 0; r < 8; ++r) x[r] = bf2f((unsigned short)v[r]);

  const size_t mofs = (size_t)row * 2048 + tid * 8;
  if (fmode == 0) {
    const unsigned int* mp = (const unsigned int*)mask + mofs;
    u32x4 m0 = *(const u32x4*)mp;
    u32x4 m1 = *(const u32x4*)(mp + 4);
#pragma unroll
    for (int r = 0; r < 4; ++r) { if (m0[r]) x[r] = 1e-9f; }
#pragma unroll
    for (int r = 0; r < 4; ++r) { if (m1[r]) x[4 + r] = 1e-9f; }
  } else if (fmode == 1) {
    const unsigned char* mp = (const unsigned char*)mask + mofs;
    us4 mb = *(const us4*)mp;  // 8 bytes
#pragma unroll
    for (int r = 0; r < 4; ++r) {
      if (mb[r] & 0x00FF) x[2 * r] = 1e-9f;
      if (mb[r] & 0xFF00) x[2 * r + 1] = 1e-9f;
    }
  } else {
    const float* mp = (const float*)mask + mofs;
    f32x4 m0 = *(const f32x4*)mp;
    f32x4 m1 = *(const f32x4*)(mp + 4);
#pragma unroll
    for (int r = 0; r < 4; ++r) { if (m0[r] != 0.0f) x[r] = 1e-9f; }
#pragma unroll
    for (int r = 0; r < 4; ++r) { if (m1[r] != 0.0f) x[4 + r] = 1e-9f; }
  }

  float m = x[0];
#pragma unroll
  for (int r = 1; r < 8; ++r) m = fmaxf(m, x[r]);
#pragma unroll
  for (int o = 32; o >= 1; o >>= 1) m = fmaxf(m, __shfl_xor(m, o));
  __shared__ float red[8];
  if (lane == 0) red[wave] = m;
  __syncthreads();
  m = fmaxf(fmaxf(red[0], red[1]), fmaxf(red[2], red[3]));
  float e[8], sum = 0.f;
#pragma unroll
  for (int r = 0; r < 8; ++r) { e[r] = expf(x[r] - m); sum += e[r]; }
#pragma unroll
  for (int o = 32; o >= 1; o >>= 1) sum += __shfl_xor(sum, o);
  if (lane == 0) red[4 + wave] = sum;
  __syncthreads();
  const float inv = 1.0f / (red[4] + red[5] + red[6] + red[7]);
  short8 o8;
#pragma unroll
  for (int r = 0; r < 8; ++r) o8[r] = (short)f2bf(e[r] * inv);
  *(short8*)(base + tid * 8) = o8;
}

// ---------------- launcher ----------------
extern "C" void kernel_launch(void* const* d_in, const int* in_sizes, int n_in,
                              void* d_out, int out_size, void* d_ws, size_t ws_size,
                              hipStream_t stream) {
  const float* tensor = (const float*)d_in[0];
  const void* mask = d_in[1];
  const float* lnw = (const float*)d_in[2];
  const float* lnb = (const float*)d_in[3];
  const float* wk = (const float*)d_in[4];
  const float* bk = (const float*)d_in[5];
  float* out = (float*)d_out;

  // ws layout (bytes):
  //   0     : Wk_t bf16 [1024][1024]                    (2 MB)
  //   2 MB  : qkv_n bf16 [8192][1024]                   (16 MB)
  //   18 MB : qkv_t bf16 [4][1024][2048]                (16 MB)
  //   34 MB : x bf16 (dead after gemm0) / scores bf16 [4][2048][2048] (32 MB)
  //   66 MB : mask-dtype flag                            (4 B)
  char* ws = (char*)d_ws;
  bf16* wkt = (bf16*)(ws);
  bf16* qkvn = (bf16*)(ws + (2ll << 20));
  bf16* qkvt = (bf16*)(ws + (18ll << 20));
  bf16* xbf = (bf16*)(ws + (34ll << 20));
  unsigned short* scores = (unsigned short*)(ws + (34ll << 20));
  int* flag = (int*)(ws + (66ll << 20));

  detect_mask_kernel<<<1, 256, 0, stream>>>((const unsigned int*)mask, flag);
  pe_ln_kernel<<<8192, 256, 0, stream>>>(tensor, lnw, lnb, xbf);
  wk_to_bf16t_kernel<<<dim3(32, 32), 256, 0, stream>>>(wk, wkt);

  // qkv = x @ Wk + bk  (M=8192, N=1024, K=1024): 8x64 = 512 blocks (2/CU)
  gemm7_kernel<0><<<dim3(8, 64, 1), 256, 0, stream>>>(
      xbf, 1024, 0, wkt, 1024, 0, 1024,
      (void*)qkvn, 1024, 0, bk, qkvt);

  // scores = qkv @ qkv^T / 32, bf16  (M=N=2048, K=1024, 4 batches): 16x16x4 = 1024
  gemm7_kernel<1><<<dim3(16, 16, 4), 256, 0, stream>>>(
      qkvn, 1024, 2048ll * 1024,
      qkvn, 1024, 2048ll * 1024, 1024,
      (void*)scores, 2048, 2048ll * 2048, nullptr, nullptr);

  // fused mask-fill(1e-9) + softmax rows, in-place bf16 -> bf16
  softmax_kernel<<<8192, 256, 0, stream>>>(scores, mask, flag);

  // out = weights @ qkv  (M=2048, N=1024, K=2048, 4 batches): 8x16x4 = 512 blocks
  gemm7_kernel<2><<<dim3(8, 16, 4), 256, 0, stream>>>(
      (const bf16*)scores, 2048, 2048ll * 2048,
      qkvt, 2048, 1024ll * 2048, 2048,
      (void*)out, 1024, 2048ll * 1024,
      nullptr, nullptr);
}

// Round 14
// 145.229 us; speedup vs baseline: 1.2119x; 1.2119x over previous
//
#include <hip/hip_runtime.h>
#include <hip/hip_bf16.h>

#define S_LEN 2048
#define D_DIM 1024

typedef float f32x4 __attribute__((ext_vector_type(4)));
typedef short short8 __attribute__((ext_vector_type(8)));
typedef unsigned short us4 __attribute__((ext_vector_type(4)));
typedef unsigned int u32x4 __attribute__((ext_vector_type(4)));

using bf16 = __hip_bfloat16;

#define GLOBAL_AS(p) ((const __attribute__((address_space(1))) void*)(p))
#define LDS_AS(p) ((__attribute__((address_space(3))) void*)(p))

static __device__ __forceinline__ unsigned short f2bf(float f) {
  bf16 h = __float2bfloat16(f);
  return *reinterpret_cast<unsigned short*>(&h);
}
static __device__ __forceinline__ float bf2f(unsigned short u) {
  unsigned int w = ((unsigned int)u) << 16;
  return __builtin_bit_cast(float, w);
}

// ---------------- mask dtype probe: 0=int32, 1=uint8, 2=float32 ----------------
__global__ void detect_mask_kernel(const unsigned int* __restrict__ m, int* __restrict__ flag) {
  __shared__ int sh;
  if (threadIdx.x == 0) sh = 0;
  __syncthreads();
  int f = 0;
  for (int i = threadIdx.x; i < 4096; i += 256) {
    unsigned int w = m[i];
    if (w == 0x3f800000u) f |= 2;
    if (w & 0xFFFFFF00u) f |= 1;
  }
  if (f) atomicOr(&sh, f);
  __syncthreads();
  if (threadIdx.x == 0) *flag = (sh & 2) ? 2 : ((sh & 1) ? 1 : 0);
}

// ---------------- fused positional-encoding + LayerNorm -> bf16 ----------------
__global__ __launch_bounds__(256) void pe_ln_kernel(
    const float* __restrict__ x, const float* __restrict__ lnw,
    const float* __restrict__ lnb, bf16* __restrict__ out) {
  const int row = blockIdx.x;
  const int s = row & (S_LEN - 1);
  const int tid = threadIdx.x;
  const float pos = (float)s;
  const float* base = x + (size_t)row * D_DIM;

  f32x4 v = *(const f32x4*)(base + tid * 4);
  float h[4];
#pragma unroll
  for (int r = 0; r < 4; ++r) {
    int d = tid * 4 + r;
    float dv = (float)d * (2.0f / 1024.0f);
    float freq = exp2f(dv * -13.287712379549449f);
    float pe = pos * freq;
    float pv = (d & 1) ? __cosf(pe) : __sinf(pe);
    h[r] = pv + v[r];
  }
  float ss = h[0] + h[1] + h[2] + h[3];
#pragma unroll
  for (int o = 32; o >= 1; o >>= 1) ss += __shfl_xor(ss, o);
  __shared__ float red[8];
  const int wave = tid >> 6, lane = tid & 63;
  if (lane == 0) red[wave] = ss;
  __syncthreads();
  const float mu = (red[0] + red[1] + red[2] + red[3]) * (1.0f / 1024.0f);
  float sq = 0.f;
#pragma unroll
  for (int r = 0; r < 4; ++r) { float d0 = h[r] - mu; sq += d0 * d0; }
#pragma unroll
  for (int o = 32; o >= 1; o >>= 1) sq += __shfl_xor(sq, o);
  if (lane == 0) red[4 + wave] = sq;
  __syncthreads();
  const float var = (red[4] + red[5] + red[6] + red[7]) * (1.0f / 1024.0f);
  const float inv = rsqrtf(var + 1e-5f);
  f32x4 wv = *(const f32x4*)(lnw + tid * 4);
  f32x4 bv = *(const f32x4*)(lnb + tid * 4);
  us4 o4;
#pragma unroll
  for (int r = 0; r < 4; ++r) o4[r] = f2bf((h[r] - mu) * inv * wv[r] + bv[r]);
  *(us4*)((unsigned short*)out + (size_t)row * D_DIM + tid * 4) = o4;
}

// ---------------- Wk fp32 [K][N] -> bf16 transposed [N][K] ----------------
__global__ __launch_bounds__(256) void wk_to_bf16t_kernel(const float* __restrict__ wk,
                                                          bf16* __restrict__ wt) {
  __shared__ float t[32][33];
  const int n0 = blockIdx.x * 32, k0 = blockIdx.y * 32;
  const int tx = threadIdx.x & 31, ty = threadIdx.x >> 5;
#pragma unroll
  for (int i = 0; i < 32; i += 8)
    t[ty + i][tx] = wk[(size_t)(k0 + ty + i) * 1024 + n0 + tx];
  __syncthreads();
#pragma unroll
  for (int i = 0; i < 32; i += 8)
    wt[(size_t)(n0 + ty + i) * 1024 + k0 + tx] = __float2bfloat16(t[tx][ty + i]);
}

// ---------------- bf16 GEMM, C = A[M][K] * B_t[N][K]^T  (r9 best-known structure) ----
// BM=256, BN=NFR*64 (256 or 128), BK=64. 512 threads = 8 waves (2M x 4N);
// per-wave output 128 x NFR*16. 2-deep LDS, stage-at-top, ONE __syncthreads per
// K-64 tile (drain has a full compute phase of slack). XOR swizzle
// slot^=(row&7) on both sides (128B rows) — measured conflict-free (r9: 0).
// EPI 0: + bias, write bf16 C row-major AND bf16 transposed copy
// EPI 1: * 1/32, write bf16 (mask applied later in softmax)
// EPI 2: plain fp32 write
template <int EPI, int NFR>
__global__ __launch_bounds__(512, 2) void gemm4_kernel(
    const bf16* __restrict__ A, int lda, long long A_bs,
    const bf16* __restrict__ B, int ldb, long long B_bs,
    int K,
    void* __restrict__ C, int ldc, long long C_bs,
    const float* __restrict__ bias, bf16* __restrict__ qkv_t) {
  constexpr int BN = NFR * 64;
  __shared__ bf16 sbuf[2][(256 + BN) * 64];  // A rows [0,256), B rows at +256*64

  const int tid = threadIdx.x;
  const int wid = tid >> 6, lane = tid & 63;
  const int wm = wid >> 2, wn = wid & 3;  // 2M x 4N wave grid

  // bijective XCD-aware swizzle (all grids have 256 blocks, %8==0)
  const int gx = gridDim.x, gy = gridDim.y;
  const int nwg = gx * gy * gridDim.z;
  int lin = (blockIdx.z * gy + blockIdx.y) * gx + blockIdx.x;
  lin = (lin & 7) * (nwg >> 3) + (lin >> 3);
  const int bx = lin % gx;
  const int by = (lin / gx) % gy;
  const int z = lin / (gx * gy);

  const int m0 = by * 256;
  const int n0 = bx * BN;

  const bf16* Ab = A + (size_t)z * A_bs;
  const bf16* Bb = B + (size_t)z * B_bs;

  // staging: one gload_lds inst covers 8 rows x 64 k (1 KB); lane L -> row
  // base + (L>>3), 16B slot (L&7) XOR (L>>3) in the source; LDS dest linear
  // (slot d of row r holds global slot d^(r&7); reader applies same XOR).
  const int grow = lane >> 3;
  const int gslot = ((lane & 7) ^ (lane >> 3)) * 8;

  // wave w stages A rows [w*32, +32) via 4 insts; B rows [w*(BN/8), +BN/8) via NFR
  const bf16* pa = Ab + (size_t)(m0 + wid * 32 + grow) * lda + gslot;
  const bf16* pb = Bb + (size_t)(n0 + wid * (BN / 8) + grow) * ldb + gslot;
  const int a_lds = (wid * 32) * 64;
  const int b_lds = 256 * 64 + (wid * (BN / 8)) * 64;

#define STAGE(bufi, kk)                                                          \
  do {                                                                           \
    _Pragma("unroll")                                                            \
    for (int i_ = 0; i_ < 4; ++i_)                                               \
      __builtin_amdgcn_global_load_lds(                                          \
          GLOBAL_AS(pa + (size_t)i_ * 8 * lda + (kk)),                           \
          LDS_AS(&sbuf[bufi][a_lds + i_ * 512]), 16, 0, 0);                      \
    _Pragma("unroll")                                                            \
    for (int j_ = 0; j_ < NFR; ++j_)                                             \
      __builtin_amdgcn_global_load_lds(                                          \
          GLOBAL_AS(pb + (size_t)j_ * 8 * ldb + (kk)),                           \
          LDS_AS(&sbuf[bufi][b_lds + j_ * 512]), 16, 0, 0);                      \
  } while (0)

  f32x4 acc[8][NFR];
#pragma unroll
  for (int i = 0; i < 8; ++i)
#pragma unroll
    for (int j = 0; j < NFR; ++j) acc[i][j] = (f32x4)(0.0f);

  // fragment reads: row = base + lrow; k-half h gives global slot (lane>>4)+h*4,
  // linear slot = global ^ (lrow&7)
  const int lrow = lane & 15;
  const int rs = lrow & 7;
  const int rdA = (wm * 128 + lrow) * 64;                  // + m*16*64 + slot*8
  const int rdB = 256 * 64 + (wn * NFR * 16 + lrow) * 64;  // + n*16*64 + slot*8

  const int NT = K >> 6;
  STAGE(0, 0);
  __syncthreads();  // vmcnt(0): buf0 fully in LDS
  int buf = 0;
  for (int kt = 0; kt < NT; ++kt) {
    if (kt + 1 < NT) STAGE(buf ^ 1, (size_t)(kt + 1) * 64);  // issue FIRST (T3)
    const bf16* S = &sbuf[buf][0];
#pragma unroll
    for (int h = 0; h < 2; ++h) {
      const int koff = (((lane >> 4) + h * 4) ^ rs) * 8;
      short8 af[8], bfr[NFR];
#pragma unroll
      for (int m = 0; m < 8; ++m) af[m] = *(const short8*)(S + rdA + m * 1024 + koff);
#pragma unroll
      for (int n = 0; n < NFR; ++n) bfr[n] = *(const short8*)(S + rdB + n * 1024 + koff);
      __builtin_amdgcn_s_setprio(1);
#pragma unroll
      for (int m = 0; m < 8; ++m)
#pragma unroll
        for (int n = 0; n < NFR; ++n)
          acc[m][n] = __builtin_amdgcn_mfma_f32_16x16x32_bf16(af[m], bfr[n], acc[m][n], 0, 0, 0);
      __builtin_amdgcn_s_setprio(0);
    }
    // one sync per K-tile: drains vmcnt (next tile staged a full compute phase
    // ago) and ensures all waves done reading buf before it's overwritten.
    __syncthreads();
    buf ^= 1;
  }
#undef STAGE

  // epilogue: C/D layout col = lane&15, row = (lane>>4)*4 + reg  [measured m89]
  const int r0 = (lane >> 4) * 4;
#pragma unroll
  for (int i = 0; i < 8; ++i) {
    const int rowl = m0 + wm * 128 + i * 16 + r0;
#pragma unroll
    for (int j = 0; j < NFR; ++j) {
      const int col = n0 + wn * NFR * 16 + j * 16 + lrow;
      if (EPI == 0) {
        const float bv = bias[col];
        us4 pack;
#pragma unroll
        for (int r = 0; r < 4; ++r) {
          unsigned short hb = f2bf(acc[i][j][r] + bv);
          ((unsigned short*)C)[(size_t)(rowl + r) * ldc + col] = hb;
          pack[r] = hb;
        }
        const int bb = rowl >> 11, s = rowl & 2047;
        *(us4*)((unsigned short*)qkv_t + (size_t)bb * (1024ll * 2048) +
                (size_t)col * 2048 + s) = pack;
      } else if (EPI == 1) {
        unsigned short* Cb = (unsigned short*)C + (size_t)z * C_bs;
#pragma unroll
        for (int r = 0; r < 4; ++r)
          Cb[(size_t)(rowl + r) * ldc + col] = f2bf(acc[i][j][r] * 0.03125f);
      } else {
#pragma unroll
        for (int r = 0; r < 4; ++r)
          ((float*)C + (size_t)z * C_bs)[(size_t)(rowl + r) * ldc + col] = acc[i][j][r];
      }
    }
  }
}

// ---------------- fused mask + in-place row softmax on bf16 scores ----------------
__global__ __launch_bounds__(256) void softmax_kernel(
    unsigned short* __restrict__ scores, const void* __restrict__ mask,
    const int* __restrict__ flagp) {
  const int row = blockIdx.x;  // 8192 rows = b*2048 + q
  const int fmode = *flagp;
  unsigned short* base = scores + (size_t)row * 2048;
  const int tid = threadIdx.x;
  const int wave = tid >> 6, lane = tid & 63;

  short8 v = *(const short8*)(base + tid * 8);
  float x[8];
#pragma unroll
  for (int r = 0; r < 8; ++r) x[r] = bf2f((unsigned short)v[r]);

  const size_t mofs = (size_t)row * 2048 + tid * 8;
  if (fmode == 0) {
    const unsigned int* mp = (const unsigned int*)mask + mofs;
    u32x4 m0 = *(const u32x4*)mp;
    u32x4 m1 = *(const u32x4*)(mp + 4);
#pragma unroll
    for (int r = 0; r < 4; ++r) { if (m0[r]) x[r] = 1e-9f; }
#pragma unroll
    for (int r = 0; r < 4; ++r) { if (m1[r]) x[4 + r] = 1e-9f; }
  } else if (fmode == 1) {
    const unsigned char* mp = (const unsigned char*)mask + mofs;
    us4 mb = *(const us4*)mp;  // 8 bytes
#pragma unroll
    for (int r = 0; r < 4; ++r) {
      if (mb[r] & 0x00FF) x[2 * r] = 1e-9f;
      if (mb[r] & 0xFF00) x[2 * r + 1] = 1e-9f;
    }
  } else {
    const float* mp = (const float*)mask + mofs;
    f32x4 m0 = *(const f32x4*)mp;
    f32x4 m1 = *(const f32x4*)(mp + 4);
#pragma unroll
    for (int r = 0; r < 4; ++r) { if (m0[r] != 0.0f) x[r] = 1e-9f; }
#pragma unroll
    for (int r = 0; r < 4; ++r) { if (m1[r] != 0.0f) x[4 + r] = 1e-9f; }
  }

  float m = x[0];
#pragma unroll
  for (int r = 1; r < 8; ++r) m = fmaxf(m, x[r]);
#pragma unroll
  for (int o = 32; o >= 1; o >>= 1) m = fmaxf(m, __shfl_xor(m, o));
  __shared__ float red[8];
  if (lane == 0) red[wave] = m;
  __syncthreads();
  m = fmaxf(fmaxf(red[0], red[1]), fmaxf(red[2], red[3]));
  float e[8], sum = 0.f;
#pragma unroll
  for (int r = 0; r < 8; ++r) { e[r] = expf(x[r] - m); sum += e[r]; }
#pragma unroll
  for (int o = 32; o >= 1; o >>= 1) sum += __shfl_xor(sum, o);
  if (lane == 0) red[4 + wave] = sum;
  __syncthreads();
  const float inv = 1.0f / (red[4] + red[5] + red[6] + red[7]);
  short8 o8;
#pragma unroll
  for (int r = 0; r < 8; ++r) o8[r] = (short)f2bf(e[r] * inv);
  *(short8*)(base + tid * 8) = o8;
}

// ---------------- launcher ----------------
extern "C" void kernel_launch(void* const* d_in, const int* in_sizes, int n_in,
                              void* d_out, int out_size, void* d_ws, size_t ws_size,
                              hipStream_t stream) {
  const float* tensor = (const float*)d_in[0];
  const void* mask = d_in[1];
  const float* lnw = (const float*)d_in[2];
  const float* lnb = (const float*)d_in[3];
  const float* wk = (const float*)d_in[4];
  const float* bk = (const float*)d_in[5];
  float* out = (float*)d_out;

  // ws layout (bytes):
  //   0     : Wk_t bf16 [1024][1024]                    (2 MB)
  //   2 MB  : qkv_n bf16 [8192][1024]                   (16 MB)
  //   18 MB : qkv_t bf16 [4][1024][2048]                (16 MB)
  //   34 MB : x bf16 (dead after gemm0) / scores bf16 [4][2048][2048] (32 MB)
  //   66 MB : mask-dtype flag                            (4 B)
  char* ws = (char*)d_ws;
  bf16* wkt = (bf16*)(ws);
  bf16* qkvn = (bf16*)(ws + (2ll << 20));
  bf16* qkvt = (bf16*)(ws + (18ll << 20));
  bf16* xbf = (bf16*)(ws + (34ll << 20));
  unsigned short* scores = (unsigned short*)(ws + (34ll << 20));
  int* flag = (int*)(ws + (66ll << 20));

  detect_mask_kernel<<<1, 256, 0, stream>>>((const unsigned int*)mask, flag);
  pe_ln_kernel<<<8192, 256, 0, stream>>>(tensor, lnw, lnb, xbf);
  wk_to_bf16t_kernel<<<dim3(32, 32), 256, 0, stream>>>(wk, wkt);

  // qkv = x @ Wk + bk  (M=8192, N=1024, K=1024): 8x32 = 256 blocks, 1/CU
  gemm4_kernel<0, 2><<<dim3(8, 32, 1), 512, 0, stream>>>(
      xbf, 1024, 0, wkt, 1024, 0, 1024,
      (void*)qkvn, 1024, 0, bk, qkvt);

  // scores = qkv @ qkv^T / 32, bf16  (M=N=2048, K=1024, 4 batches): 8x8x4 = 256
  gemm4_kernel<1, 4><<<dim3(8, 8, 4), 512, 0, stream>>>(
      qkvn, 1024, 2048ll * 1024,
      qkvn, 1024, 2048ll * 1024, 1024,
      (void*)scores, 2048, 2048ll * 2048, nullptr, nullptr);

  // fused mask-fill(1e-9) + softmax rows, in-place bf16 -> bf16
  softmax_kernel<<<8192, 256, 0, stream>>>(scores, mask, flag);

  // out = weights @ qkv  (M=2048, N=1024, K=2048, 4 batches): 8x8x4 = 256
  gemm4_kernel<2, 2><<<dim3(8, 8, 4), 512, 0, stream>>>(
      (const bf16*)scores, 2048, 2048ll * 2048,
      qkvt, 2048, 1024ll * 2048, 2048,
      (void*)out, 1024, 2048ll * 1024,
      nullptr, nullptr);
}

// Round 15
// 140.155 us; speedup vs baseline: 1.2558x; 1.0362x over previous
//
#include <hip/hip_runtime.h>
#include <hip/hip_bf16.h>

#define S_LEN 2048
#define D_DIM 1024

typedef float f32x4 __attribute__((ext_vector_type(4)));
typedef short short8 __attribute__((ext_vector_type(8)));
typedef unsigned short us4 __attribute__((ext_vector_type(4)));
typedef unsigned int u32x4 __attribute__((ext_vector_type(4)));

using bf16 = __hip_bfloat16;

#define GLOBAL_AS(p) ((const __attribute__((address_space(1))) void*)(p))
#define LDS_AS(p) ((__attribute__((address_space(3))) void*)(p))

static __device__ __forceinline__ unsigned short f2bf(float f) {
  bf16 h = __float2bfloat16(f);
  return *reinterpret_cast<unsigned short*>(&h);
}
static __device__ __forceinline__ float bf2f(unsigned short u) {
  unsigned int w = ((unsigned int)u) << 16;
  return __builtin_bit_cast(float, w);
}

// ---------------- fused prep: PE+LayerNorm (blocks 0..8191), Wk transpose
// (blocks 8192..9215), mask dtype probe (block 9216) ----------------
__global__ __launch_bounds__(256) void prep_kernel(
    const float* __restrict__ x, const float* __restrict__ lnw,
    const float* __restrict__ lnb, bf16* __restrict__ out,
    const float* __restrict__ wk, bf16* __restrict__ wt,
    const unsigned int* __restrict__ maskw, int* __restrict__ flag) {
  const int bid = blockIdx.x;
  const int tid = threadIdx.x;

  if (bid < 8192) {
    // -------- positional encoding + LayerNorm -> bf16 --------
    const int row = bid;
    const int s = row & (S_LEN - 1);
    const float pos = (float)s;
    const float* base = x + (size_t)row * D_DIM;

    f32x4 v = *(const f32x4*)(base + tid * 4);
    float h[4];
#pragma unroll
    for (int r = 0; r < 4; ++r) {
      int d = tid * 4 + r;
      float dv = (float)d * (2.0f / 1024.0f);
      float freq = exp2f(dv * -13.287712379549449f);
      float pe = pos * freq;
      float pv = (d & 1) ? __cosf(pe) : __sinf(pe);
      h[r] = pv + v[r];
    }
    float ss = h[0] + h[1] + h[2] + h[3];
#pragma unroll
    for (int o = 32; o >= 1; o >>= 1) ss += __shfl_xor(ss, o);
    __shared__ float red[8];
    const int wave = tid >> 6, lane = tid & 63;
    if (lane == 0) red[wave] = ss;
    __syncthreads();
    const float mu = (red[0] + red[1] + red[2] + red[3]) * (1.0f / 1024.0f);
    float sq = 0.f;
#pragma unroll
    for (int r = 0; r < 4; ++r) { float d0 = h[r] - mu; sq += d0 * d0; }
#pragma unroll
    for (int o = 32; o >= 1; o >>= 1) sq += __shfl_xor(sq, o);
    if (lane == 0) red[4 + wave] = sq;
    __syncthreads();
    const float var = (red[4] + red[5] + red[6] + red[7]) * (1.0f / 1024.0f);
    const float inv = rsqrtf(var + 1e-5f);
    f32x4 wv = *(const f32x4*)(lnw + tid * 4);
    f32x4 bv = *(const f32x4*)(lnb + tid * 4);
    us4 o4;
#pragma unroll
    for (int r = 0; r < 4; ++r) o4[r] = f2bf((h[r] - mu) * inv * wv[r] + bv[r]);
    *(us4*)((unsigned short*)out + (size_t)row * D_DIM + tid * 4) = o4;
  } else if (bid < 9216) {
    // -------- Wk fp32 [K][N] -> bf16 transposed [N][K] --------
    __shared__ float t[32][33];
    const int idx = bid - 8192;
    const int n0 = (idx & 31) * 32, k0 = (idx >> 5) * 32;
    const int tx = tid & 31, ty = tid >> 5;
#pragma unroll
    for (int i = 0; i < 32; i += 8)
      t[ty + i][tx] = wk[(size_t)(k0 + ty + i) * 1024 + n0 + tx];
    __syncthreads();
#pragma unroll
    for (int i = 0; i < 32; i += 8)
      wt[(size_t)(n0 + ty + i) * 1024 + k0 + tx] = __float2bfloat16(t[tx][ty + i]);
  } else {
    // -------- mask dtype probe: 0=int32, 1=uint8, 2=float32 --------
    __shared__ int sh;
    if (tid == 0) sh = 0;
    __syncthreads();
    int f = 0;
    for (int i = tid; i < 4096; i += 256) {
      unsigned int w = maskw[i];
      if (w == 0x3f800000u) f |= 2;
      if (w & 0xFFFFFF00u) f |= 1;
    }
    if (f) atomicOr(&sh, f);
    __syncthreads();
    if (tid == 0) *flag = (sh & 2) ? 2 : ((sh & 1) ? 1 : 0);
  }
}

// ---------------- bf16 GEMM, C = A[M][K] * B_t[N][K]^T  (r9 best-known structure) ----
// BM=256, BN=NFR*64 (256 or 128), BK=64. 512 threads = 8 waves (2M x 4N);
// per-wave output 128 x NFR*16. 2-deep LDS, stage-at-top, ONE __syncthreads per
// K-64 tile (drain has a full compute phase of slack). XOR swizzle
// slot^=(row&7) on both sides (128B rows) — measured conflict-free (r9/r14: 0).
// setprio REMOVED this round (m190: setprio hurts lockstep GEMM).
// EPI 0: + bias, write bf16 C row-major AND bf16 transposed copy
// EPI 1: * 1/32, write bf16 (mask applied later in softmax)
// EPI 2: plain fp32 write
template <int EPI, int NFR>
__global__ __launch_bounds__(512, 2) void gemm4_kernel(
    const bf16* __restrict__ A, int lda, long long A_bs,
    const bf16* __restrict__ B, int ldb, long long B_bs,
    int K,
    void* __restrict__ C, int ldc, long long C_bs,
    const float* __restrict__ bias, bf16* __restrict__ qkv_t) {
  constexpr int BN = NFR * 64;
  __shared__ bf16 sbuf[2][(256 + BN) * 64];  // A rows [0,256), B rows at +256*64

  const int tid = threadIdx.x;
  const int wid = tid >> 6, lane = tid & 63;
  const int wm = wid >> 2, wn = wid & 3;  // 2M x 4N wave grid

  // bijective XCD-aware swizzle (all grids have 256 blocks, %8==0)
  const int gx = gridDim.x, gy = gridDim.y;
  const int nwg = gx * gy * gridDim.z;
  int lin = (blockIdx.z * gy + blockIdx.y) * gx + blockIdx.x;
  lin = (lin & 7) * (nwg >> 3) + (lin >> 3);
  const int bx = lin % gx;
  const int by = (lin / gx) % gy;
  const int z = lin / (gx * gy);

  const int m0 = by * 256;
  const int n0 = bx * BN;

  const bf16* Ab = A + (size_t)z * A_bs;
  const bf16* Bb = B + (size_t)z * B_bs;

  // staging: one gload_lds inst covers 8 rows x 64 k (1 KB); lane L -> row
  // base + (L>>3), 16B slot (L&7) XOR (L>>3) in the source; LDS dest linear
  // (slot d of row r holds global slot d^(r&7); reader applies same XOR).
  const int grow = lane >> 3;
  const int gslot = ((lane & 7) ^ (lane >> 3)) * 8;

  // wave w stages A rows [w*32, +32) via 4 insts; B rows [w*(BN/8), +BN/8) via NFR
  const bf16* pa = Ab + (size_t)(m0 + wid * 32 + grow) * lda + gslot;
  const bf16* pb = Bb + (size_t)(n0 + wid * (BN / 8) + grow) * ldb + gslot;
  const int a_lds = (wid * 32) * 64;
  const int b_lds = 256 * 64 + (wid * (BN / 8)) * 64;

#define STAGE(bufi, kk)                                                          \
  do {                                                                           \
    _Pragma("unroll")                                                            \
    for (int i_ = 0; i_ < 4; ++i_)                                               \
      __builtin_amdgcn_global_load_lds(                                          \
          GLOBAL_AS(pa + (size_t)i_ * 8 * lda + (kk)),                           \
          LDS_AS(&sbuf[bufi][a_lds + i_ * 512]), 16, 0, 0);                      \
    _Pragma("unroll")                                                            \
    for (int j_ = 0; j_ < NFR; ++j_)                                             \
      __builtin_amdgcn_global_load_lds(                                          \
          GLOBAL_AS(pb + (size_t)j_ * 8 * ldb + (kk)),                           \
          LDS_AS(&sbuf[bufi][b_lds + j_ * 512]), 16, 0, 0);                      \
  } while (0)

  f32x4 acc[8][NFR];
#pragma unroll
  for (int i = 0; i < 8; ++i)
#pragma unroll
    for (int j = 0; j < NFR; ++j) acc[i][j] = (f32x4)(0.0f);

  // fragment reads: row = base + lrow; k-half h gives global slot (lane>>4)+h*4,
  // linear slot = global ^ (lrow&7)
  const int lrow = lane & 15;
  const int rs = lrow & 7;
  const int rdA = (wm * 128 + lrow) * 64;                  // + m*16*64 + slot*8
  const int rdB = 256 * 64 + (wn * NFR * 16 + lrow) * 64;  // + n*16*64 + slot*8

  const int NT = K >> 6;
  STAGE(0, 0);
  __syncthreads();  // vmcnt(0): buf0 fully in LDS
  int buf = 0;
  for (int kt = 0; kt < NT; ++kt) {
    if (kt + 1 < NT) STAGE(buf ^ 1, (size_t)(kt + 1) * 64);  // issue FIRST (T3)
    const bf16* S = &sbuf[buf][0];
#pragma unroll
    for (int h = 0; h < 2; ++h) {
      const int koff = (((lane >> 4) + h * 4) ^ rs) * 8;
      short8 af[8], bfr[NFR];
#pragma unroll
      for (int m = 0; m < 8; ++m) af[m] = *(const short8*)(S + rdA + m * 1024 + koff);
#pragma unroll
      for (int n = 0; n < NFR; ++n) bfr[n] = *(const short8*)(S + rdB + n * 1024 + koff);
#pragma unroll
      for (int m = 0; m < 8; ++m)
#pragma unroll
        for (int n = 0; n < NFR; ++n)
          acc[m][n] = __builtin_amdgcn_mfma_f32_16x16x32_bf16(af[m], bfr[n], acc[m][n], 0, 0, 0);
    }
    // one sync per K-tile: drains vmcnt (next tile staged a full compute phase
    // ago) and ensures all waves done reading buf before it's overwritten.
    __syncthreads();
    buf ^= 1;
  }
#undef STAGE

  // epilogue: C/D layout col = lane&15, row = (lane>>4)*4 + reg  [measured m89]
  const int r0 = (lane >> 4) * 4;
#pragma unroll
  for (int i = 0; i < 8; ++i) {
    const int rowl = m0 + wm * 128 + i * 16 + r0;
#pragma unroll
    for (int j = 0; j < NFR; ++j) {
      const int col = n0 + wn * NFR * 16 + j * 16 + lrow;
      if (EPI == 0) {
        const float bv = bias[col];
        us4 pack;
#pragma unroll
        for (int r = 0; r < 4; ++r) {
          unsigned short hb = f2bf(acc[i][j][r] + bv);
          ((unsigned short*)C)[(size_t)(rowl + r) * ldc + col] = hb;
          pack[r] = hb;
        }
        const int bb = rowl >> 11, s = rowl & 2047;
        *(us4*)((unsigned short*)qkv_t + (size_t)bb * (1024ll * 2048) +
                (size_t)col * 2048 + s) = pack;
      } else if (EPI == 1) {
        unsigned short* Cb = (unsigned short*)C + (size_t)z * C_bs;
#pragma unroll
        for (int r = 0; r < 4; ++r)
          Cb[(size_t)(rowl + r) * ldc + col] = f2bf(acc[i][j][r] * 0.03125f);
      } else {
#pragma unroll
        for (int r = 0; r < 4; ++r)
          ((float*)C + (size_t)z * C_bs)[(size_t)(rowl + r) * ldc + col] = acc[i][j][r];
      }
    }
  }
}

// ---------------- fused mask + in-place row softmax on bf16 scores ----------------
__global__ __launch_bounds__(256) void softmax_kernel(
    unsigned short* __restrict__ scores, const void* __restrict__ mask,
    const int* __restrict__ flagp) {
  const int row = blockIdx.x;  // 8192 rows = b*2048 + q
  const int fmode = *flagp;
  unsigned short* base = scores + (size_t)row * 2048;
  const int tid = threadIdx.x;
  const int wave = tid >> 6, lane = tid & 63;

  short8 v = *(const short8*)(base + tid * 8);
  float x[8];
#pragma unroll
  for (int r = 0; r < 8; ++r) x[r] = bf2f((unsigned short)v[r]);

  const size_t mofs = (size_t)row * 2048 + tid * 8;
  if (fmode == 0) {
    const unsigned int* mp = (const unsigned int*)mask + mofs;
    u32x4 m0 = *(const u32x4*)mp;
    u32x4 m1 = *(const u32x4*)(mp + 4);
#pragma unroll
    for (int r = 0; r < 4; ++r) { if (m0[r]) x[r] = 1e-9f; }
#pragma unroll
    for (int r = 0; r < 4; ++r) { if (m1[r]) x[4 + r] = 1e-9f; }
  } else if (fmode == 1) {
    const unsigned char* mp = (const unsigned char*)mask + mofs;
    us4 mb = *(const us4*)mp;  // 8 bytes
#pragma unroll
    for (int r = 0; r < 4; ++r) {
      if (mb[r] & 0x00FF) x[2 * r] = 1e-9f;
      if (mb[r] & 0xFF00) x[2 * r + 1] = 1e-9f;
    }
  } else {
    const float* mp = (const float*)mask + mofs;
    f32x4 m0 = *(const f32x4*)mp;
    f32x4 m1 = *(const f32x4*)(mp + 4);
#pragma unroll
    for (int r = 0; r < 4; ++r) { if (m0[r] != 0.0f) x[r] = 1e-9f; }
#pragma unroll
    for (int r = 0; r < 4; ++r) { if (m1[r] != 0.0f) x[4 + r] = 1e-9f; }
  }

  float m = x[0];
#pragma unroll
  for (int r = 1; r < 8; ++r) m = fmaxf(m, x[r]);
#pragma unroll
  for (int o = 32; o >= 1; o >>= 1) m = fmaxf(m, __shfl_xor(m, o));
  __shared__ float red[8];
  if (lane == 0) red[wave] = m;
  __syncthreads();
  m = fmaxf(fmaxf(red[0], red[1]), fmaxf(red[2], red[3]));
  float e[8], sum = 0.f;
#pragma unroll
  for (int r = 0; r < 8; ++r) { e[r] = expf(x[r] - m); sum += e[r]; }
#pragma unroll
  for (int o = 32; o >= 1; o >>= 1) sum += __shfl_xor(sum, o);
  if (lane == 0) red[4 + wave] = sum;
  __syncthreads();
  const float inv = 1.0f / (red[4] + red[5] + red[6] + red[7]);
  short8 o8;
#pragma unroll
  for (int r = 0; r < 8; ++r) o8[r] = (short)f2bf(e[r] * inv);
  *(short8*)(base + tid * 8) = o8;
}

// ---------------- launcher ----------------
extern "C" void kernel_launch(void* const* d_in, const int* in_sizes, int n_in,
                              void* d_out, int out_size, void* d_ws, size_t ws_size,
                              hipStream_t stream) {
  const float* tensor = (const float*)d_in[0];
  const void* mask = d_in[1];
  const float* lnw = (const float*)d_in[2];
  const float* lnb = (const float*)d_in[3];
  const float* wk = (const float*)d_in[4];
  const float* bk = (const float*)d_in[5];
  float* out = (float*)d_out;

  // ws layout (bytes):
  //   0     : Wk_t bf16 [1024][1024]                    (2 MB)
  //   2 MB  : qkv_n bf16 [8192][1024]                   (16 MB)
  //   18 MB : qkv_t bf16 [4][1024][2048]                (16 MB)
  //   34 MB : x bf16 (dead after gemm0) / scores bf16 [4][2048][2048] (32 MB)
  //   66 MB : mask-dtype flag                            (4 B)
  char* ws = (char*)d_ws;
  bf16* wkt = (bf16*)(ws);
  bf16* qkvn = (bf16*)(ws + (2ll << 20));
  bf16* qkvt = (bf16*)(ws + (18ll << 20));
  bf16* xbf = (bf16*)(ws + (34ll << 20));
  unsigned short* scores = (unsigned short*)(ws + (34ll << 20));
  int* flag = (int*)(ws + (66ll << 20));

  // fused prep: pe_ln (8192 blocks) + Wk transpose (1024) + mask probe (1)
  prep_kernel<<<9217, 256, 0, stream>>>(tensor, lnw, lnb, xbf, wk, wkt,
                                        (const unsigned int*)mask, flag);

  // qkv = x @ Wk + bk  (M=8192, N=1024, K=1024): 8x32 = 256 blocks, 1/CU
  gemm4_kernel<0, 2><<<dim3(8, 32, 1), 512, 0, stream>>>(
      xbf, 1024, 0, wkt, 1024, 0, 1024,
      (void*)qkvn, 1024, 0, bk, qkvt);

  // scores = qkv @ qkv^T / 32, bf16  (M=N=2048, K=1024, 4 batches): 8x8x4 = 256
  gemm4_kernel<1, 4><<<dim3(8, 8, 4), 512, 0, stream>>>(
      qkvn, 1024, 2048ll * 1024,
      qkvn, 1024, 2048ll * 1024, 1024,
      (void*)scores, 2048, 2048ll * 2048, nullptr, nullptr);

  // fused mask-fill(1e-9) + softmax rows, in-place bf16 -> bf16
  softmax_kernel<<<8192, 256, 0, stream>>>(scores, mask, flag);

  // out = weights @ qkv  (M=2048, N=1024, K=2048, 4 batches): 8x8x4 = 256
  gemm4_kernel<2, 2><<<dim3(8, 8, 4), 512, 0, stream>>>(
      (const bf16*)scores, 2048, 2048ll * 2048,
      qkvt, 2048, 1024ll * 2048, 2048,
      (void*)out, 1024, 2048ll * 1024,
      nullptr, nullptr);
}